// Round 14
// baseline (451.314 us; speedup 1.0000x reference)
//
#include <hip/hip_runtime.h>

typedef unsigned int uint;
typedef unsigned char uchar;
typedef unsigned short ushort;
typedef unsigned long long ull;

#define F_IN 64
#define HD 32
#define NCLS 2
#define BN_EPS 1e-5f
#define SCHUNK 1024
#define NCOPY 8
#define FIX_SCALE 1073741824.0f            // 2^30
#define FIX_INV   9.313225746154785e-10f   // 2^-30
#define MASK40 ((1ULL << 40) - 1)

__device__ __forceinline__ ull ld64(const int2* p) {
    return *reinterpret_cast<const ull*>(p);
}
__device__ __forceinline__ ushort f2bf(float f) {
    uint u = __float_as_uint(f);
    u = (u + 0x7FFFu + ((u >> 16) & 1u)) >> 16;   // RNE
    return (ushort)u;
}
__device__ __forceinline__ float bf2f(ushort b) {
    return __uint_as_float((uint)b << 16);
}
// e4m3fn encode of pre-scaled x (no subnormals stored: |x|<2^-6 -> 0; clamp 448)
__device__ __forceinline__ uchar f2e4(float x) {
    uint u = __float_as_uint(x);
    uint s = u & 0x80000000u;
    uint mag = u & 0x7fffffffu;
    if (mag < 0x3c800000u) return (uchar)(s >> 24);        // |x| < 2^-6 -> +-0
    if (mag > 0x43e00000u) mag = 0x43e00000u;              // clamp to 448
    uint r = mag + 0x000FFFFFu + ((mag >> 20) & 1u);       // RNE into 3-bit mant
    if (r > 0x43e00000u) r = 0x43e00000u;
    uint E = r >> 23;
    return (uchar)((s >> 24) | ((E - 120u) << 3) | ((r >> 20) & 7u));
}
// branchless decode (rest==0 decodes to 2^-7 -> <=0.0005 after /16 descale)
__device__ __forceinline__ float e42f(uchar b) {
    uint s = ((uint)b & 0x80u) << 24;
    uint rest = (uint)b & 0x7fu;
    return __uint_as_float(s | ((rest << 20) + 0x3c000000u));
}

// ---------- 8-copy fused histogram: copy k = blockIdx&7 (no rank output) ----------
__global__ void hist64_kernel(const int* __restrict__ ei, const float* __restrict__ w,
                              ull* __restrict__ packed8, int E, int n) {
    int e = blockIdx.x * blockDim.x + threadIdx.x;
    if (e >= E) return;
    int k = blockIdx.x & (NCOPY - 1);
    int c = ei[E + e];
    ull fx = (ull)(w[e] * FIX_SCALE + 0.5f);
    atomicAdd(&packed8[(size_t)k * n + c], (1ULL << 40) | fx);
}

// ---------- scan phase A: per-chunk total-count sums over 8 copies; fused dis ----------
__global__ void scanA_kernel(const ull* __restrict__ packed8,
                             int* __restrict__ partial, float* __restrict__ dis, int n) {
    __shared__ int red[256];
    int base = blockIdx.x * SCHUNK;
    int tid = threadIdx.x;
    int s = 0;
    for (int i = tid; i < SCHUNK; i += 256) {
        int idx = base + i;
        if (idx < n) {
            int cnt = 0;
            ull fxs = 0;
#pragma unroll
            for (int k = 0; k < NCOPY; k++) {
                ull p = packed8[(size_t)k * n + idx];
                cnt += (int)(p >> 40);
                fxs += (p & MASK40);
            }
            s += cnt;
            float deg = (float)fxs * FIX_INV;
            dis[idx] = rsqrtf(deg + 1.0f);   // self-loop weight 1; arg >= 1
        }
    }
    red[tid] = s;
    __syncthreads();
    for (int off = 128; off > 0; off >>= 1) {
        if (tid < off) red[tid] += red[tid + off];
        __syncthreads();
    }
    if (tid == 0) partial[blockIdx.x] = red[0];
}

// ---------- scan phase C (folds B): local partial-scan + per-chunk scan -> offs, cursor8 ----------
__global__ void scanC_kernel(const ull* __restrict__ packed8, const int* __restrict__ partial,
                             int* __restrict__ offs, int* __restrict__ cursor8, int n, int scb) {
    __shared__ int lds[256];
    __shared__ int chunkBase, totalE;
    int tid = threadIdx.x;
    // local exclusive scan of the <=256 chunk partials
    int v = (tid < scb) ? partial[tid] : 0;
    lds[tid] = v;
    __syncthreads();
    for (int off = 1; off < 256; off <<= 1) {
        int t = (tid >= off) ? lds[tid - off] : 0;
        __syncthreads();
        lds[tid] += t;
        __syncthreads();
    }
    if (tid == 0) {
        chunkBase = lds[blockIdx.x] - partial[blockIdx.x];   // exclusive at this chunk
        totalE = lds[scb - 1];
    }
    __syncthreads();
    // per-chunk scan (reuse lds)
    int i0 = blockIdx.x * SCHUNK + tid * 4;
    int cnt[4][NCOPY];
    int tot[4] = {0, 0, 0, 0};
#pragma unroll
    for (int t = 0; t < 4; t++) {
        int idx = i0 + t;
#pragma unroll
        for (int k = 0; k < NCOPY; k++) {
            int c = (idx < n) ? (int)(packed8[(size_t)k * n + idx] >> 40) : 0;
            cnt[t][k] = c;
            tot[t] += c;
        }
    }
    int tsum = tot[0] + tot[1] + tot[2] + tot[3];
    lds[tid] = tsum;
    __syncthreads();
    for (int off = 1; off < 256; off <<= 1) {
        int t = (tid >= off) ? lds[tid - off] : 0;
        __syncthreads();
        lds[tid] += t;
        __syncthreads();
    }
    int run = chunkBase + lds[tid] - tsum;
#pragma unroll
    for (int t = 0; t < 4; t++) {
        int idx = i0 + t;
        if (idx < n) {
            offs[idx] = run;
            int b = run;
#pragma unroll
            for (int k = 0; k < NCOPY; k++) {
                cursor8[(size_t)idx * NCOPY + k] = b;
                b += cnt[t][k];
            }
            run = b;
        }
    }
    if (blockIdx.x == 0 && tid == 0) offs[n] = totalE;
}

// ---------- fused: blocks [0,eb) fill CSR via atomic cursors; blocks [eb,..) gemm1 ----------
__global__ void fill_gemm1_kernel(const int* __restrict__ ei, const float* __restrict__ w,
                                  int* __restrict__ cursor8,
                                  int2* __restrict__ centry, int E, int eb,
                                  const float* __restrict__ X, const float* __restrict__ W,
                                  const float* __restrict__ dis, ushort* __restrict__ Hb,
                                  float* __restrict__ statsCur, int n) {
    if ((int)blockIdx.x < eb) {
        int e = blockIdx.x * blockDim.x + threadIdx.x;
        if (e >= E) return;
        int k = blockIdx.x & (NCOPY - 1);           // must match hist64 grid mapping
        int r = ei[e], c = ei[E + e];
        int pos = atomicAdd(&cursor8[(size_t)c * NCOPY + k], 1);
        centry[pos] = make_int2(r, __float_as_int(w[e]));
        return;
    }
    // ---- gemm1 part ----
    __shared__ float Wl[F_IN * HD];
    int gb = (int)blockIdx.x - eb;
    for (int i = threadIdx.x; i < F_IN * HD; i += blockDim.x) Wl[i] = W[i];
    if (gb == 0) {
        for (int i = threadIdx.x; i < NCOPY * 64; i += blockDim.x) statsCur[i] = 0.0f;
    }
    __syncthreads();
    int idx = gb * (int)blockDim.x + (int)threadIdx.x;
    if (idx >= n * HD) return;
    int node = idx >> 5, h = idx & 31;
    const float4* xr4 = reinterpret_cast<const float4*>(X + (size_t)node * F_IN);
    float acc = 0.0f;
#pragma unroll
    for (int q = 0; q < F_IN / 4; q++) {
        float4 v4 = xr4[q];
        float vs[4] = {v4.x, v4.y, v4.z, v4.w};
#pragma unroll
        for (int j = 0; j < 4; j++) {
            acc += vs[j] * Wl[(q * 4 + j) * HD + h];
        }
    }
    Hb[idx] = f2bf(acc * dis[node]);
}

// ---------- small GEMM (layers 2,3): table = ((bn(X) @ W) * dis); bf16 or fp8(x16) ----------
template <bool FP8>
__global__ void gemm_bn_kernel(const float* __restrict__ X, const float* __restrict__ W,
                               const float* __restrict__ statsPrev, const float* __restrict__ g,
                               const float* __restrict__ be, const float* __restrict__ dis,
                               ushort* __restrict__ Hb, uchar* __restrict__ Hb8,
                               float* __restrict__ statsCur, int n) {
    __shared__ float Wl[HD * HD];
    __shared__ float scl[64];
    for (int i = threadIdx.x; i < HD * HD; i += blockDim.x) Wl[i] = W[i];
    if (threadIdx.x < 32) {
        int h = threadIdx.x;
        float sm = 0.f, sq = 0.f;
#pragma unroll
        for (int k = 0; k < NCOPY; k++) {
            sm += statsPrev[k * 64 + h];
            sq += statsPrev[k * 64 + 32 + h];
        }
        float invn = 1.0f / (float)n;
        float mean = sm * invn;
        float var = sq * invn - mean * mean;   // biased
        float sca = rsqrtf(var + BN_EPS) * g[h];
        scl[h] = sca;
        scl[32 + h] = be[h] - mean * sca;
    }
    if (blockIdx.x == 0) {
        for (int i = threadIdx.x; i < NCOPY * 64; i += blockDim.x) statsCur[i] = 0.0f;
    }
    __syncthreads();
    int idx = blockIdx.x * blockDim.x + threadIdx.x;
    if (idx >= n * HD) return;
    int node = idx >> 5, h = idx & 31;
    const float4* xr4 = reinterpret_cast<const float4*>(X + (size_t)node * HD);
    float acc = 0.0f;
#pragma unroll
    for (int q = 0; q < HD / 4; q++) {
        float4 v4 = xr4[q];
        float vs[4] = {v4.x, v4.y, v4.z, v4.w};
#pragma unroll
        for (int j = 0; j < 4; j++) {
            int k = q * 4 + j;
            acc += (vs[j] * scl[k] + scl[32 + k]) * Wl[k * HD + h];
        }
    }
    float v = acc * dis[node];
    if (FP8) Hb8[idx] = f2e4(v * 16.0f);
    else     Hb[idx]  = f2bf(v);
}

// ====== V4n-bf16<NPW,DEEP8>: contiguous halves; 4- or 8-deep consecutive preloads ======
template <int NPW, bool DEEP8>
__global__ void aggV4n_kernel(const ushort* __restrict__ hb, const int* __restrict__ offs,
                              const int2* __restrict__ centry, const float* __restrict__ dis,
                              const float* __restrict__ bias, float* __restrict__ y,
                              float* __restrict__ stats, int n) {
    int wave = threadIdx.x >> 6, lane = threadIdx.x & 63, sub = lane >> 5, h = lane & 31;
    float bv = bias[h];
    float lsum = 0.f, lsq = 0.f;
    int base = (blockIdx.x * 4 + wave) * NPW;
    for (int t = 0; t < NPW; t++) {
        int node = base + t;
        if (node >= n) break;
        int s = offs[node], e2 = offs[node + 1];
        int len = e2 - s;
        int half = (len + 1) >> 1;
        int j    = sub ? (s + half) : s;          // contiguous halves
        int jend = sub ? e2 : (s + half);
        float dd = dis[node];
        float a0 = 0.f, a1 = 0.f, a2 = 0.f, a3 = 0.f;
        if (sub == 0) a0 = bf2f(hb[(size_t)node * HD + h]);   // self-loop
        if (DEEP8) {
            float a4 = 0.f, a5 = 0.f, a6 = 0.f, a7 = 0.f;
            for (; j + 7 < jend; j += 8) {
                ull p0 = ld64(centry + j);
                ull p1 = ld64(centry + j + 1);
                ull p2 = ld64(centry + j + 2);
                ull p3 = ld64(centry + j + 3);
                ull p4 = ld64(centry + j + 4);
                ull p5 = ld64(centry + j + 5);
                ull p6 = ld64(centry + j + 6);
                ull p7 = ld64(centry + j + 7);
                a0 += bf2f(hb[(size_t)(uint)p0 * HD + h]) * __uint_as_float((uint)(p0 >> 32));
                a1 += bf2f(hb[(size_t)(uint)p1 * HD + h]) * __uint_as_float((uint)(p1 >> 32));
                a2 += bf2f(hb[(size_t)(uint)p2 * HD + h]) * __uint_as_float((uint)(p2 >> 32));
                a3 += bf2f(hb[(size_t)(uint)p3 * HD + h]) * __uint_as_float((uint)(p3 >> 32));
                a4 += bf2f(hb[(size_t)(uint)p4 * HD + h]) * __uint_as_float((uint)(p4 >> 32));
                a5 += bf2f(hb[(size_t)(uint)p5 * HD + h]) * __uint_as_float((uint)(p5 >> 32));
                a6 += bf2f(hb[(size_t)(uint)p6 * HD + h]) * __uint_as_float((uint)(p6 >> 32));
                a7 += bf2f(hb[(size_t)(uint)p7 * HD + h]) * __uint_as_float((uint)(p7 >> 32));
            }
            a0 += a4; a1 += a5; a2 += a6; a3 += a7;
        }
        for (; j + 3 < jend; j += 4) {
            ull p0 = ld64(centry + j);
            ull p1 = ld64(centry + j + 1);
            ull p2 = ld64(centry + j + 2);
            ull p3 = ld64(centry + j + 3);
            a0 += bf2f(hb[(size_t)(uint)p0 * HD + h]) * __uint_as_float((uint)(p0 >> 32));
            a1 += bf2f(hb[(size_t)(uint)p1 * HD + h]) * __uint_as_float((uint)(p1 >> 32));
            a2 += bf2f(hb[(size_t)(uint)p2 * HD + h]) * __uint_as_float((uint)(p2 >> 32));
            a3 += bf2f(hb[(size_t)(uint)p3 * HD + h]) * __uint_as_float((uint)(p3 >> 32));
        }
        for (; j < jend; j++) {
            ull p0 = ld64(centry + j);
            a0 += bf2f(hb[(size_t)(uint)p0 * HD + h]) * __uint_as_float((uint)(p0 >> 32));
        }
        a0 += a1 + a2 + a3;
        a0 += __shfl_xor(a0, 32, 64);
        float yv = fmaxf(fmaf(a0, dd, bv), 0.f);
        if (sub == 0) {
            y[(size_t)node * HD + h] = yv;
            lsum += yv; lsq += yv * yv;
        }
    }
    __shared__ float ls[4][32], lq[4][32];
    if (sub == 0) { ls[wave][h] = lsum; lq[wave][h] = lsq; }
    __syncthreads();
    if (threadIdx.x < 32) {
        int k = blockIdx.x & (NCOPY - 1);
        float a = ls[0][threadIdx.x] + ls[1][threadIdx.x] + ls[2][threadIdx.x] + ls[3][threadIdx.x];
        float b = lq[0][threadIdx.x] + lq[1][threadIdx.x] + lq[2][threadIdx.x] + lq[3][threadIdx.x];
        atomicAdd(&stats[k * 64 + threadIdx.x], a);
        atomicAdd(&stats[k * 64 + 32 + threadIdx.x], b);
    }
}

// ====== V4n-fp8<NPW>: same structure, 1-byte table gathers, x1/16 folded into dis ======
template <int NPW>
__global__ void aggV4n8_kernel(const uchar* __restrict__ hb8, const int* __restrict__ offs,
                               const int2* __restrict__ centry, const float* __restrict__ dis,
                               const float* __restrict__ bias, float* __restrict__ y,
                               float* __restrict__ stats, int n) {
    int wave = threadIdx.x >> 6, lane = threadIdx.x & 63, sub = lane >> 5, h = lane & 31;
    float bv = bias[h];
    float lsum = 0.f, lsq = 0.f;
    int base = (blockIdx.x * 4 + wave) * NPW;
    for (int t = 0; t < NPW; t++) {
        int node = base + t;
        if (node >= n) break;
        int s = offs[node], e2 = offs[node + 1];
        int len = e2 - s;
        int half = (len + 1) >> 1;
        int j    = sub ? (s + half) : s;          // contiguous halves
        int jend = sub ? e2 : (s + half);
        float dd = dis[node] * 0.0625f;           // descale fp8's x16
        float a0 = 0.f, a1 = 0.f, a2 = 0.f, a3 = 0.f;
        if (sub == 0) a0 = e42f(hb8[(size_t)node * HD + h]);  // self-loop (scaled)
        for (; j + 3 < jend; j += 4) {
            ull p0 = ld64(centry + j);
            ull p1 = ld64(centry + j + 1);
            ull p2 = ld64(centry + j + 2);
            ull p3 = ld64(centry + j + 3);
            a0 += e42f(hb8[(size_t)(uint)p0 * HD + h]) * __uint_as_float((uint)(p0 >> 32));
            a1 += e42f(hb8[(size_t)(uint)p1 * HD + h]) * __uint_as_float((uint)(p1 >> 32));
            a2 += e42f(hb8[(size_t)(uint)p2 * HD + h]) * __uint_as_float((uint)(p2 >> 32));
            a3 += e42f(hb8[(size_t)(uint)p3 * HD + h]) * __uint_as_float((uint)(p3 >> 32));
        }
        for (; j < jend; j++) {
            ull p0 = ld64(centry + j);
            a0 += e42f(hb8[(size_t)(uint)p0 * HD + h]) * __uint_as_float((uint)(p0 >> 32));
        }
        a0 += a1 + a2 + a3;
        a0 += __shfl_xor(a0, 32, 64);
        float yv = fmaxf(fmaf(a0, dd, bv), 0.f);
        if (sub == 0) {
            y[(size_t)node * HD + h] = yv;
            lsum += yv; lsq += yv * yv;
        }
    }
    __shared__ float ls[4][32], lq[4][32];
    if (sub == 0) { ls[wave][h] = lsum; lq[wave][h] = lsq; }
    __syncthreads();
    if (threadIdx.x < 32) {
        int k = blockIdx.x & (NCOPY - 1);
        float a = ls[0][threadIdx.x] + ls[1][threadIdx.x] + ls[2][threadIdx.x] + ls[3][threadIdx.x];
        float b = lq[0][threadIdx.x] + lq[1][threadIdx.x] + lq[2][threadIdx.x] + lq[3][threadIdx.x];
        atomicAdd(&stats[k * 64 + threadIdx.x], a);
        atomicAdd(&stats[k * 64 + 32 + threadIdx.x], b);
    }
}

// ---------- final linear: bn(y1..3) concat [N,96] @ [96,2] + bl; BN from 8-copy stats ----------
__global__ void final_kernel(const float* __restrict__ y1, const float* __restrict__ y2,
                             const float* __restrict__ y3,
                             const float* __restrict__ s1, const float* __restrict__ s2,
                             const float* __restrict__ s3,
                             const float* __restrict__ g1, const float* __restrict__ be1,
                             const float* __restrict__ g2, const float* __restrict__ be2,
                             const float* __restrict__ g3, const float* __restrict__ be3,
                             const float* __restrict__ Wl, const float* __restrict__ bl,
                             float* __restrict__ out, int n) {
    __shared__ float Ws[96 * NCLS];
    __shared__ float scs[3][64];
    __shared__ float bs[NCLS];
    for (int i = threadIdx.x; i < 96 * NCLS; i += blockDim.x) Ws[i] = Wl[i];
    if (threadIdx.x < 96) {
        int L = threadIdx.x >> 5, h = threadIdx.x & 31;
        const float* st = (L == 0) ? s1 : (L == 1) ? s2 : s3;
        const float* gg = (L == 0) ? g1 : (L == 1) ? g2 : g3;
        const float* bb = (L == 0) ? be1 : (L == 1) ? be2 : be3;
        float sm = 0.f, sq = 0.f;
#pragma unroll
        for (int k = 0; k < NCOPY; k++) {
            sm += st[k * 64 + h];
            sq += st[k * 64 + 32 + h];
        }
        float invn = 1.0f / (float)n;
        float mean = sm * invn;
        float var = sq * invn - mean * mean;
        float sca = rsqrtf(var + BN_EPS) * gg[h];
        scs[L][h] = sca;
        scs[L][32 + h] = bb[h] - mean * sca;
    }
    if (threadIdx.x < NCLS) bs[threadIdx.x] = bl[threadIdx.x];
    __syncthreads();
    int i = blockIdx.x * blockDim.x + threadIdx.x;
    if (i >= n) return;
    float a0 = bs[0], a1 = bs[1];
    const float* ys[3] = {y1 + (size_t)i * HD, y2 + (size_t)i * HD, y3 + (size_t)i * HD};
#pragma unroll
    for (int L = 0; L < 3; L++) {
        const float4* r4 = reinterpret_cast<const float4*>(ys[L]);
#pragma unroll
        for (int q = 0; q < HD / 4; q++) {
            float4 v4 = r4[q];
            float vs[4] = {v4.x, v4.y, v4.z, v4.w};
#pragma unroll
            for (int j = 0; j < 4; j++) {
                int h = q * 4 + j;
                float v = vs[j] * scs[L][h] + scs[L][32 + h];
                a0 += v * Ws[(L * 32 + h) * 2];
                a1 += v * Ws[(L * 32 + h) * 2 + 1];
            }
        }
    }
    out[(size_t)i * 2] = a0;
    out[(size_t)i * 2 + 1] = a1;
}

extern "C" void kernel_launch(void* const* d_in, const int* in_sizes, int n_in,
                              void* d_out, int out_size, void* d_ws, size_t ws_size,
                              hipStream_t stream) {
    const float* x  = (const float*)d_in[0];
    const int*   ei = (const int*)d_in[1];
    const float* ew = (const float*)d_in[2];
    const float* W1 = (const float*)d_in[3];  const float* b1  = (const float*)d_in[4];
    const float* g1 = (const float*)d_in[5];  const float* be1 = (const float*)d_in[6];
    const float* W2 = (const float*)d_in[7];  const float* b2  = (const float*)d_in[8];
    const float* g2 = (const float*)d_in[9];  const float* be2 = (const float*)d_in[10];
    const float* W3 = (const float*)d_in[11]; const float* b3  = (const float*)d_in[12];
    const float* g3 = (const float*)d_in[13]; const float* be3 = (const float*)d_in[14];
    const float* Wl = (const float*)d_in[15]; const float* bl  = (const float*)d_in[16];

    int n = in_sizes[0] / F_IN;
    int E = in_sizes[1] / 2;

    char* ws = (char*)d_ws;
    auto alloc = [&](size_t bytes) -> char* {
        char* p = ws;
        ws += (bytes + 255) / 256 * 256;
        return p;
    };
    ull*    packed8 = (ull*)alloc((size_t)NCOPY * n * 8);
    float*  dis     = (float*)alloc((size_t)n * 4);
    int*    offs    = (int*)alloc((size_t)(n + 1) * 4);
    int*    cursor8 = (int*)alloc((size_t)n * NCOPY * 4);
    int*    partial = (int*)alloc(256 * 4);
    int2*   centry  = (int2*)alloc((size_t)E * 8);
    ushort* hb      = (ushort*)alloc((size_t)n * HD * 2);
    uchar*  hb8     = (uchar*)alloc((size_t)n * HD);
    float*  y1      = (float*)alloc((size_t)n * HD * 4);
    float*  y2      = (float*)alloc((size_t)n * HD * 4);
    float*  y3      = (float*)alloc((size_t)n * HD * 4);
    float*  stats1  = (float*)alloc(NCOPY * 64 * 4);
    float*  stats2  = (float*)alloc(NCOPY * 64 * 4);
    float*  stats3  = (float*)alloc(NCOPY * 64 * 4);

    hipMemsetAsync(packed8, 0, (size_t)NCOPY * n * 8, stream);

    int eb  = (E + 255) / 256;
    int nb  = (n + 255) / 256;
    int nhb = (n * HD + 255) / 256;
    int scb = (n + SCHUNK - 1) / SCHUNK;            // 98 for n=100000 (<=256 required)
    int agb = (n + 63) / 64;                        // NPW=16 grid

    hist64_kernel<<<eb, 256, 0, stream>>>(ei, ew, packed8, E, n);
    scanA_kernel<<<scb, 256, 0, stream>>>(packed8, partial, dis, n);
    scanC_kernel<<<scb, 256, 0, stream>>>(packed8, partial, offs, cursor8, n, scb);

    // fused: fill (blocks [0,eb)) + gemm1 (blocks [eb, eb+nhb))
    fill_gemm1_kernel<<<eb + nhb, 256, 0, stream>>>(ei, ew, cursor8, centry, E, eb,
                                                    x, W1, dis, hb, stats1, n);

    // layer 1 — bf16 agg 4-deep (control)
    aggV4n_kernel<16, false><<<agb, 256, 0, stream>>>(hb, offs, centry, dis, b1, y1, stats1, n);
    // layer 2 — fp8 table (3.2 MB, per-XCD L2-resident)
    gemm_bn_kernel<true><<<nhb, 256, 0, stream>>>(y1, W2, stats1, g1, be1, dis, hb, hb8, stats2, n);
    aggV4n8_kernel<16><<<agb, 256, 0, stream>>>(hb8, offs, centry, dis, b2, y2, stats2, n);
    // layer 3 — bf16 agg 8-deep (A/B)
    gemm_bn_kernel<false><<<nhb, 256, 0, stream>>>(y2, W3, stats2, g3, be3, dis, hb, hb8, stats3, n);
    aggV4n_kernel<16, true><<<agb, 256, 0, stream>>>(hb, offs, centry, dis, b3, y3, stats3, n);

    final_kernel<<<nb, 256, 0, stream>>>(y1, y2, y3, stats1, stats2, stats3,
                                         g1, be1, g2, be2, g3, be3, Wl, bl, (float*)d_out, n);
}

// Round 15
// 376.647 us; speedup vs baseline: 1.1982x; 1.1982x over previous
//
#include <hip/hip_runtime.h>

typedef unsigned int uint;
typedef unsigned char uchar;
typedef unsigned short ushort;
typedef unsigned long long ull;

#define F_IN 64
#define HD 32
#define NCLS 2
#define BN_EPS 1e-5f
#define SCHUNK 1024
#define NCOPY 8
#define FIX_SCALE 1073741824.0f            // 2^30
#define FIX_INV   9.313225746154785e-10f   // 2^-30
#define MASK40 ((1ULL << 40) - 1)

__device__ __forceinline__ ull ld64(const int2* p) {
    return *reinterpret_cast<const ull*>(p);
}
__device__ __forceinline__ ushort f2bf(float f) {
    uint u = __float_as_uint(f);
    u = (u + 0x7FFFu + ((u >> 16) & 1u)) >> 16;   // RNE
    return (ushort)u;
}
__device__ __forceinline__ float bf2f(ushort b) {
    return __uint_as_float((uint)b << 16);
}
// e4m3fn encode of pre-scaled x (no subnormals stored: |x|<2^-6 -> 0; clamp 448)
__device__ __forceinline__ uchar f2e4(float x) {
    uint u = __float_as_uint(x);
    uint s = u & 0x80000000u;
    uint mag = u & 0x7fffffffu;
    if (mag < 0x3c800000u) return (uchar)(s >> 24);        // |x| < 2^-6 -> +-0
    if (mag > 0x43e00000u) mag = 0x43e00000u;              // clamp to 448
    uint r = mag + 0x000FFFFFu + ((mag >> 20) & 1u);       // RNE into 3-bit mant
    if (r > 0x43e00000u) r = 0x43e00000u;
    uint E = r >> 23;
    return (uchar)((s >> 24) | ((E - 120u) << 3) | ((r >> 20) & 7u));
}
// branchless decode (rest==0 decodes to 2^-7 -> <=0.0005 after /16 descale)
__device__ __forceinline__ float e42f(uchar b) {
    uint s = ((uint)b & 0x80u) << 24;
    uint rest = (uint)b & 0x7fu;
    return __uint_as_float(s | ((rest << 20) + 0x3c000000u));
}

// ---------- 8-copy fused histogram: copy k = blockIdx&7; epos = per-copy rank ----------
__global__ void hist64_kernel(const int* __restrict__ ei, const float* __restrict__ w,
                              ull* __restrict__ packed8, ushort* __restrict__ epos,
                              int E, int n) {
    int e = blockIdx.x * blockDim.x + threadIdx.x;
    if (e >= E) return;
    int k = blockIdx.x & (NCOPY - 1);
    int c = ei[E + e];
    ull fx = (ull)(w[e] * FIX_SCALE + 0.5f);
    ull old = atomicAdd(&packed8[(size_t)k * n + c], (1ULL << 40) | fx);
    epos[e] = (ushort)(old >> 40);
}

// ---------- scan phase A: per-chunk total-count sums over 8 copies; fused dis ----------
__global__ void scanA_kernel(const ull* __restrict__ packed8,
                             int* __restrict__ partial, float* __restrict__ dis, int n) {
    __shared__ int red[256];
    int base = blockIdx.x * SCHUNK;
    int tid = threadIdx.x;
    int s = 0;
    for (int i = tid; i < SCHUNK; i += 256) {
        int idx = base + i;
        if (idx < n) {
            int cnt = 0;
            ull fxs = 0;
#pragma unroll
            for (int k = 0; k < NCOPY; k++) {
                ull p = packed8[(size_t)k * n + idx];
                cnt += (int)(p >> 40);
                fxs += (p & MASK40);
            }
            s += cnt;
            float deg = (float)fxs * FIX_INV;
            dis[idx] = rsqrtf(deg + 1.0f);   // self-loop weight 1; arg >= 1
        }
    }
    red[tid] = s;
    __syncthreads();
    for (int off = 128; off > 0; off >>= 1) {
        if (tid < off) red[tid] += red[tid + off];
        __syncthreads();
    }
    if (tid == 0) partial[blockIdx.x] = red[0];
}

// ---------- scan phase C (folds B): local partial-scan + per-chunk scan -> offs, base8 ----------
__global__ void scanC_kernel(const ull* __restrict__ packed8, const int* __restrict__ partial,
                             int* __restrict__ offs, int* __restrict__ base8, int n, int scb) {
    __shared__ int lds[256];
    __shared__ int chunkBase, totalE;
    int tid = threadIdx.x;
    // local exclusive scan of the <=256 chunk partials
    int v = (tid < scb) ? partial[tid] : 0;
    lds[tid] = v;
    __syncthreads();
    for (int off = 1; off < 256; off <<= 1) {
        int t = (tid >= off) ? lds[tid - off] : 0;
        __syncthreads();
        lds[tid] += t;
        __syncthreads();
    }
    if (tid == 0) {
        chunkBase = lds[blockIdx.x] - partial[blockIdx.x];   // exclusive at this chunk
        totalE = lds[scb - 1];
    }
    __syncthreads();
    // per-chunk scan (reuse lds)
    int i0 = blockIdx.x * SCHUNK + tid * 4;
    int cnt[4][NCOPY];
    int tot[4] = {0, 0, 0, 0};
#pragma unroll
    for (int t = 0; t < 4; t++) {
        int idx = i0 + t;
#pragma unroll
        for (int k = 0; k < NCOPY; k++) {
            int c = (idx < n) ? (int)(packed8[(size_t)k * n + idx] >> 40) : 0;
            cnt[t][k] = c;
            tot[t] += c;
        }
    }
    int tsum = tot[0] + tot[1] + tot[2] + tot[3];
    lds[tid] = tsum;
    __syncthreads();
    for (int off = 1; off < 256; off <<= 1) {
        int t = (tid >= off) ? lds[tid - off] : 0;
        __syncthreads();
        lds[tid] += t;
        __syncthreads();
    }
    int run = chunkBase + lds[tid] - tsum;
#pragma unroll
    for (int t = 0; t < 4; t++) {
        int idx = i0 + t;
        if (idx < n) {
            offs[idx] = run;
            int b = run;
#pragma unroll
            for (int k = 0; k < NCOPY; k++) {
                base8[(size_t)idx * NCOPY + k] = b;
                b += cnt[t][k];
            }
            run = b;
        }
    }
    if (blockIdx.x == 0 && tid == 0) offs[n] = totalE;
}

// ---------- fused: blocks [0,eb) fill CSR atomic-free; blocks [eb,..) gemm1 ----------
__global__ void fill_gemm1_kernel(const int* __restrict__ ei, const float* __restrict__ w,
                                  const int* __restrict__ base8, const ushort* __restrict__ epos,
                                  int2* __restrict__ centry, int E, int eb,
                                  const float* __restrict__ X, const float* __restrict__ W,
                                  const float* __restrict__ dis, ushort* __restrict__ Hb,
                                  float* __restrict__ statsCur, int n) {
    if ((int)blockIdx.x < eb) {
        int e = blockIdx.x * blockDim.x + threadIdx.x;
        if (e >= E) return;
        int k = blockIdx.x & (NCOPY - 1);           // must match hist64 grid mapping
        int r = ei[e], c = ei[E + e];
        int pos = base8[(size_t)c * NCOPY + k] + (int)epos[e];
        centry[pos] = make_int2(r, __float_as_int(w[e]));
        return;
    }
    // ---- gemm1 part ----
    __shared__ float Wl[F_IN * HD];
    int gb = (int)blockIdx.x - eb;
    for (int i = threadIdx.x; i < F_IN * HD; i += blockDim.x) Wl[i] = W[i];
    if (gb == 0) {
        for (int i = threadIdx.x; i < NCOPY * 64; i += blockDim.x) statsCur[i] = 0.0f;
    }
    __syncthreads();
    int idx = gb * (int)blockDim.x + (int)threadIdx.x;
    if (idx >= n * HD) return;
    int node = idx >> 5, h = idx & 31;
    const float4* xr4 = reinterpret_cast<const float4*>(X + (size_t)node * F_IN);
    float acc = 0.0f;
#pragma unroll
    for (int q = 0; q < F_IN / 4; q++) {
        float4 v4 = xr4[q];
        float vs[4] = {v4.x, v4.y, v4.z, v4.w};
#pragma unroll
        for (int j = 0; j < 4; j++) {
            acc += vs[j] * Wl[(q * 4 + j) * HD + h];
        }
    }
    Hb[idx] = f2bf(acc * dis[node]);
}

// ---------- small GEMM (layers 2,3): table = ((bn(X) @ W) * dis); bf16 or fp8(x16) ----------
template <bool FP8>
__global__ void gemm_bn_kernel(const float* __restrict__ X, const float* __restrict__ W,
                               const float* __restrict__ statsPrev, const float* __restrict__ g,
                               const float* __restrict__ be, const float* __restrict__ dis,
                               ushort* __restrict__ Hb, uchar* __restrict__ Hb8,
                               float* __restrict__ statsCur, int n) {
    __shared__ float Wl[HD * HD];
    __shared__ float scl[64];
    for (int i = threadIdx.x; i < HD * HD; i += blockDim.x) Wl[i] = W[i];
    if (threadIdx.x < 32) {
        int h = threadIdx.x;
        float sm = 0.f, sq = 0.f;
#pragma unroll
        for (int k = 0; k < NCOPY; k++) {
            sm += statsPrev[k * 64 + h];
            sq += statsPrev[k * 64 + 32 + h];
        }
        float invn = 1.0f / (float)n;
        float mean = sm * invn;
        float var = sq * invn - mean * mean;   // biased
        float sca = rsqrtf(var + BN_EPS) * g[h];
        scl[h] = sca;
        scl[32 + h] = be[h] - mean * sca;
    }
    if (blockIdx.x == 0) {
        for (int i = threadIdx.x; i < NCOPY * 64; i += blockDim.x) statsCur[i] = 0.0f;
    }
    __syncthreads();
    int idx = blockIdx.x * blockDim.x + threadIdx.x;
    if (idx >= n * HD) return;
    int node = idx >> 5, h = idx & 31;
    const float4* xr4 = reinterpret_cast<const float4*>(X + (size_t)node * HD);
    float acc = 0.0f;
#pragma unroll
    for (int q = 0; q < HD / 4; q++) {
        float4 v4 = xr4[q];
        float vs[4] = {v4.x, v4.y, v4.z, v4.w};
#pragma unroll
        for (int j = 0; j < 4; j++) {
            int k = q * 4 + j;
            acc += (vs[j] * scl[k] + scl[32 + k]) * Wl[k * HD + h];
        }
    }
    float v = acc * dis[node];
    if (FP8) Hb8[idx] = f2e4(v * 16.0f);
    else     Hb[idx]  = f2bf(v);
}

// ====== V4n-bf16: contiguous halves, 4 consecutive ld64 preload -> 4 indep bf16 gathers ======
__global__ void aggV4n_kernel(const ushort* __restrict__ hb, const int* __restrict__ offs,
                              const int2* __restrict__ centry, const float* __restrict__ dis,
                              const float* __restrict__ bias, float* __restrict__ y,
                              float* __restrict__ stats, int n) {
    const int NPW = 16;
    int wave = threadIdx.x >> 6, lane = threadIdx.x & 63, sub = lane >> 5, h = lane & 31;
    float bv = bias[h];
    float lsum = 0.f, lsq = 0.f;
    int base = (blockIdx.x * 4 + wave) * NPW;
    for (int t = 0; t < NPW; t++) {
        int node = base + t;
        if (node >= n) break;
        int s = offs[node], e2 = offs[node + 1];
        int len = e2 - s;
        int half = (len + 1) >> 1;
        int j    = sub ? (s + half) : s;          // contiguous halves
        int jend = sub ? e2 : (s + half);
        float dd = dis[node];
        float a0 = 0.f, a1 = 0.f, a2 = 0.f, a3 = 0.f;
        if (sub == 0) a0 = bf2f(hb[(size_t)node * HD + h]);   // self-loop
        for (; j + 3 < jend; j += 4) {
            ull p0 = ld64(centry + j);
            ull p1 = ld64(centry + j + 1);
            ull p2 = ld64(centry + j + 2);
            ull p3 = ld64(centry + j + 3);
            a0 += bf2f(hb[(size_t)(uint)p0 * HD + h]) * __uint_as_float((uint)(p0 >> 32));
            a1 += bf2f(hb[(size_t)(uint)p1 * HD + h]) * __uint_as_float((uint)(p1 >> 32));
            a2 += bf2f(hb[(size_t)(uint)p2 * HD + h]) * __uint_as_float((uint)(p2 >> 32));
            a3 += bf2f(hb[(size_t)(uint)p3 * HD + h]) * __uint_as_float((uint)(p3 >> 32));
        }
        for (; j < jend; j++) {
            ull p0 = ld64(centry + j);
            a0 += bf2f(hb[(size_t)(uint)p0 * HD + h]) * __uint_as_float((uint)(p0 >> 32));
        }
        a0 += a1 + a2 + a3;
        a0 += __shfl_xor(a0, 32, 64);
        float yv = fmaxf(fmaf(a0, dd, bv), 0.f);
        if (sub == 0) {
            y[(size_t)node * HD + h] = yv;
            lsum += yv; lsq += yv * yv;
        }
    }
    __shared__ float ls[4][32], lq[4][32];
    if (sub == 0) { ls[wave][h] = lsum; lq[wave][h] = lsq; }
    __syncthreads();
    if (threadIdx.x < 32) {
        int k = blockIdx.x & (NCOPY - 1);
        float a = ls[0][threadIdx.x] + ls[1][threadIdx.x] + ls[2][threadIdx.x] + ls[3][threadIdx.x];
        float b = lq[0][threadIdx.x] + lq[1][threadIdx.x] + lq[2][threadIdx.x] + lq[3][threadIdx.x];
        atomicAdd(&stats[k * 64 + threadIdx.x], a);
        atomicAdd(&stats[k * 64 + 32 + threadIdx.x], b);
    }
}

// ====== V4n-fp8: same structure, 1-byte table gathers, x1/16 folded into dis ======
__global__ void aggV4n8_kernel(const uchar* __restrict__ hb8, const int* __restrict__ offs,
                               const int2* __restrict__ centry, const float* __restrict__ dis,
                               const float* __restrict__ bias, float* __restrict__ y,
                               float* __restrict__ stats, int n) {
    const int NPW = 16;
    int wave = threadIdx.x >> 6, lane = threadIdx.x & 63, sub = lane >> 5, h = lane & 31;
    float bv = bias[h];
    float lsum = 0.f, lsq = 0.f;
    int base = (blockIdx.x * 4 + wave) * NPW;
    for (int t = 0; t < NPW; t++) {
        int node = base + t;
        if (node >= n) break;
        int s = offs[node], e2 = offs[node + 1];
        int len = e2 - s;
        int half = (len + 1) >> 1;
        int j    = sub ? (s + half) : s;          // contiguous halves
        int jend = sub ? e2 : (s + half);
        float dd = dis[node] * 0.0625f;           // descale fp8's x16
        float a0 = 0.f, a1 = 0.f, a2 = 0.f, a3 = 0.f;
        if (sub == 0) a0 = e42f(hb8[(size_t)node * HD + h]);  // self-loop (scaled)
        for (; j + 3 < jend; j += 4) {
            ull p0 = ld64(centry + j);
            ull p1 = ld64(centry + j + 1);
            ull p2 = ld64(centry + j + 2);
            ull p3 = ld64(centry + j + 3);
            a0 += e42f(hb8[(size_t)(uint)p0 * HD + h]) * __uint_as_float((uint)(p0 >> 32));
            a1 += e42f(hb8[(size_t)(uint)p1 * HD + h]) * __uint_as_float((uint)(p1 >> 32));
            a2 += e42f(hb8[(size_t)(uint)p2 * HD + h]) * __uint_as_float((uint)(p2 >> 32));
            a3 += e42f(hb8[(size_t)(uint)p3 * HD + h]) * __uint_as_float((uint)(p3 >> 32));
        }
        for (; j < jend; j++) {
            ull p0 = ld64(centry + j);
            a0 += e42f(hb8[(size_t)(uint)p0 * HD + h]) * __uint_as_float((uint)(p0 >> 32));
        }
        a0 += a1 + a2 + a3;
        a0 += __shfl_xor(a0, 32, 64);
        float yv = fmaxf(fmaf(a0, dd, bv), 0.f);
        if (sub == 0) {
            y[(size_t)node * HD + h] = yv;
            lsum += yv; lsq += yv * yv;
        }
    }
    __shared__ float ls[4][32], lq[4][32];
    if (sub == 0) { ls[wave][h] = lsum; lq[wave][h] = lsq; }
    __syncthreads();
    if (threadIdx.x < 32) {
        int k = blockIdx.x & (NCOPY - 1);
        float a = ls[0][threadIdx.x] + ls[1][threadIdx.x] + ls[2][threadIdx.x] + ls[3][threadIdx.x];
        float b = lq[0][threadIdx.x] + lq[1][threadIdx.x] + lq[2][threadIdx.x] + lq[3][threadIdx.x];
        atomicAdd(&stats[k * 64 + threadIdx.x], a);
        atomicAdd(&stats[k * 64 + 32 + threadIdx.x], b);
    }
}

// ---------- final linear: bn(y1..3) concat [N,96] @ [96,2] + bl; BN from 8-copy stats ----------
__global__ void final_kernel(const float* __restrict__ y1, const float* __restrict__ y2,
                             const float* __restrict__ y3,
                             const float* __restrict__ s1, const float* __restrict__ s2,
                             const float* __restrict__ s3,
                             const float* __restrict__ g1, const float* __restrict__ be1,
                             const float* __restrict__ g2, const float* __restrict__ be2,
                             const float* __restrict__ g3, const float* __restrict__ be3,
                             const float* __restrict__ Wl, const float* __restrict__ bl,
                             float* __restrict__ out, int n) {
    __shared__ float Ws[96 * NCLS];
    __shared__ float scs[3][64];
    __shared__ float bs[NCLS];
    for (int i = threadIdx.x; i < 96 * NCLS; i += blockDim.x) Ws[i] = Wl[i];
    if (threadIdx.x < 96) {
        int L = threadIdx.x >> 5, h = threadIdx.x & 31;
        const float* st = (L == 0) ? s1 : (L == 1) ? s2 : s3;
        const float* gg = (L == 0) ? g1 : (L == 1) ? g2 : g3;
        const float* bb = (L == 0) ? be1 : (L == 1) ? be2 : be3;
        float sm = 0.f, sq = 0.f;
#pragma unroll
        for (int k = 0; k < NCOPY; k++) {
            sm += st[k * 64 + h];
            sq += st[k * 64 + 32 + h];
        }
        float invn = 1.0f / (float)n;
        float mean = sm * invn;
        float var = sq * invn - mean * mean;
        float sca = rsqrtf(var + BN_EPS) * gg[h];
        scs[L][h] = sca;
        scs[L][32 + h] = bb[h] - mean * sca;
    }
    if (threadIdx.x < NCLS) bs[threadIdx.x] = bl[threadIdx.x];
    __syncthreads();
    int i = blockIdx.x * blockDim.x + threadIdx.x;
    if (i >= n) return;
    float a0 = bs[0], a1 = bs[1];
    const float* ys[3] = {y1 + (size_t)i * HD, y2 + (size_t)i * HD, y3 + (size_t)i * HD};
#pragma unroll
    for (int L = 0; L < 3; L++) {
        const float4* r4 = reinterpret_cast<const float4*>(ys[L]);
#pragma unroll
        for (int q = 0; q < HD / 4; q++) {
            float4 v4 = r4[q];
            float vs[4] = {v4.x, v4.y, v4.z, v4.w};
#pragma unroll
            for (int j = 0; j < 4; j++) {
                int h = q * 4 + j;
                float v = vs[j] * scs[L][h] + scs[L][32 + h];
                a0 += v * Ws[(L * 32 + h) * 2];
                a1 += v * Ws[(L * 32 + h) * 2 + 1];
            }
        }
    }
    out[(size_t)i * 2] = a0;
    out[(size_t)i * 2 + 1] = a1;
}

extern "C" void kernel_launch(void* const* d_in, const int* in_sizes, int n_in,
                              void* d_out, int out_size, void* d_ws, size_t ws_size,
                              hipStream_t stream) {
    const float* x  = (const float*)d_in[0];
    const int*   ei = (const int*)d_in[1];
    const float* ew = (const float*)d_in[2];
    const float* W1 = (const float*)d_in[3];  const float* b1  = (const float*)d_in[4];
    const float* g1 = (const float*)d_in[5];  const float* be1 = (const float*)d_in[6];
    const float* W2 = (const float*)d_in[7];  const float* b2  = (const float*)d_in[8];
    const float* g2 = (const float*)d_in[9];  const float* be2 = (const float*)d_in[10];
    const float* W3 = (const float*)d_in[11]; const float* b3  = (const float*)d_in[12];
    const float* g3 = (const float*)d_in[13]; const float* be3 = (const float*)d_in[14];
    const float* Wl = (const float*)d_in[15]; const float* bl  = (const float*)d_in[16];

    int n = in_sizes[0] / F_IN;
    int E = in_sizes[1] / 2;

    char* ws = (char*)d_ws;
    auto alloc = [&](size_t bytes) -> char* {
        char* p = ws;
        ws += (bytes + 255) / 256 * 256;
        return p;
    };
    ull*    packed8 = (ull*)alloc((size_t)NCOPY * n * 8);
    float*  dis     = (float*)alloc((size_t)n * 4);
    int*    offs    = (int*)alloc((size_t)(n + 1) * 4);
    int*    base8   = (int*)alloc((size_t)n * NCOPY * 4);
    int*    partial = (int*)alloc(256 * 4);
    ushort* epos    = (ushort*)alloc((size_t)E * 2);
    int2*   centry  = (int2*)alloc((size_t)E * 8);
    ushort* hb      = (ushort*)alloc((size_t)n * HD * 2);
    uchar*  hb8     = (uchar*)alloc((size_t)n * HD);
    float*  y1      = (float*)alloc((size_t)n * HD * 4);
    float*  y2      = (float*)alloc((size_t)n * HD * 4);
    float*  y3      = (float*)alloc((size_t)n * HD * 4);
    float*  stats1  = (float*)alloc(NCOPY * 64 * 4);
    float*  stats2  = (float*)alloc(NCOPY * 64 * 4);
    float*  stats3  = (float*)alloc(NCOPY * 64 * 4);

    hipMemsetAsync(packed8, 0, (size_t)NCOPY * n * 8, stream);

    int eb  = (E + 255) / 256;
    int nb  = (n + 255) / 256;
    int nhb = (n * HD + 255) / 256;
    int scb = (n + SCHUNK - 1) / SCHUNK;            // 98 for n=100000 (<=256 required)
    int agb = (n + 63) / 64;                        // NPW=16 grid

    hist64_kernel<<<eb, 256, 0, stream>>>(ei, ew, packed8, epos, E, n);
    scanA_kernel<<<scb, 256, 0, stream>>>(packed8, partial, dis, n);
    scanC_kernel<<<scb, 256, 0, stream>>>(packed8, partial, offs, base8, n, scb);

    // fused: fill (blocks [0,eb)) + gemm1 (blocks [eb, eb+nhb))
    fill_gemm1_kernel<<<eb + nhb, 256, 0, stream>>>(ei, ew, base8, epos, centry, E, eb,
                                                    x, W1, dis, hb, stats1, n);

    // layer 1 — bf16 agg (verified 83 us shape)
    aggV4n_kernel<<<agb, 256, 0, stream>>>(hb, offs, centry, dis, b1, y1, stats1, n);
    // layer 2 — fp8 table (3.2 MB, per-XCD L2-resident, ~50 us)
    gemm_bn_kernel<true><<<nhb, 256, 0, stream>>>(y1, W2, stats1, g1, be1, dis, hb, hb8, stats2, n);
    aggV4n8_kernel<<<agb, 256, 0, stream>>>(hb8, offs, centry, dis, b2, y2, stats2, n);
    // layer 3 — bf16 agg
    gemm_bn_kernel<false><<<nhb, 256, 0, stream>>>(y2, W3, stats2, g3, be3, dis, hb, hb8, stats3, n);
    aggV4n_kernel<<<agb, 256, 0, stream>>>(hb, offs, centry, dis, b3, y3, stats3, n);

    final_kernel<<<nb, 256, 0, stream>>>(y1, y2, y3, stats1, stats2, stats3,
                                         g1, be1, g2, be2, g3, be3, Wl, bl, (float*)d_out, n);
}